// Round 8
// baseline (61.575 us; speedup 1.0000x reference)
//
#include <hip/hip_runtime.h>
#include <hip/hip_bf16.h>

#define NN 4096
#define SJ 8
#define JCH (NN / SJ)        // 512
#define JSTEP 64
#define NSTEPS (JCH / JSTEP) // 8
#define ROWS 64
#define LOG2E 1.44269504f

typedef __attribute__((ext_vector_type(4))) float f32x4;
typedef __attribute__((ext_vector_type(4))) int i32x4;
typedef __attribute__((ext_vector_type(4))) unsigned int u32x4;
typedef __attribute__((ext_vector_type(8))) short short8;

// packed bf16 pair: (lo=bf16(a), hi=bf16(b)) in one dword (v_cvt_pk_bf16_f32)
__device__ __forceinline__ unsigned pk2(float a, float b) {
    float2 t; t.x = a; t.y = b;
    __hip_bfloat162 h = __float22bfloat162_rn(t);
    unsigned r;
    __builtin_memcpy(&r, &h, 4);
    return r;
}

__device__ __forceinline__ short8 load8_bf(const float* __restrict__ p) {
    f32x4 a = *(const f32x4*)p;
    f32x4 b = *(const f32x4*)(p + 4);
    u32x4 v = {pk2(a[0], a[1]), pk2(a[2], a[3]), pk2(b[0], b[1]), pk2(b[2], b[3])};
    return __builtin_bit_cast(short8, v);
}

// Kernel 1: h = x @ W^T (bf16 MFMA). Epilogue:
//   Rt[h][i] = exp(-0.8*es_i)  (f32; exp(es) factor cancels in softmax)
//   Bt[h][j] = exp(ed_j), Dt[h][j] = exp(0.2*ed_j)   (f32 tables)
//   hT[h*32+d][j] = bf16 h, transposed via per-wave LDS tile (coalesced stores)
__global__ __launch_bounds__(256) void k1_proj(
        const float* __restrict__ x, const float* __restrict__ W,
        const float* __restrict__ asrc, const float* __restrict__ adst,
        unsigned short* __restrict__ hT, float* __restrict__ Rt,
        float* __restrict__ Bt, float* __restrict__ Dt) {
    __shared__ unsigned short ttile[4][32][16];   // 4 KB
    const int ibase = blockIdx.x * 16;
    const int w = threadIdx.x >> 6;
    const int lane = threadIdx.x & 63;
    const int grp = lane >> 4, li = lane & 15;

    const float* xrow = x + (ibase + li) * 128;
    const float* w0 = W + (w * 32 + li) * 128;
    const float* w1 = W + (w * 32 + 16 + li) * 128;

    f32x4 c0 = {0.f, 0.f, 0.f, 0.f}, c1 = {0.f, 0.f, 0.f, 0.f};
#pragma unroll
    for (int ko = 0; ko < 128; ko += 32) {
        const int kk = ko + grp * 8;
        short8 a = load8_bf(xrow + kk);
        short8 b0 = load8_bf(w0 + kk);
        short8 b1 = load8_bf(w1 + kk);
        c0 = __builtin_amdgcn_mfma_f32_16x16x32_bf16(a, b0, c0, 0, 0, 0);
        c1 = __builtin_amdgcn_mfma_f32_16x16x32_bf16(a, b1, c1, 0, 0, 0);
    }
    const float as0 = asrc[w * 32 + li], as1 = asrc[w * 32 + 16 + li];
    const float ad0 = adst[w * 32 + li], ad1 = adst[w * 32 + 16 + li];
    float pes[4], ped[4];
#pragma unroll
    for (int r = 0; r < 4; ++r) {
        pes[r] = c0[r] * as0 + c1[r] * as1;
        ped[r] = c0[r] * ad0 + c1[r] * ad1;
    }
#pragma unroll
    for (int m = 1; m < 16; m <<= 1) {
#pragma unroll
        for (int r = 0; r < 4; ++r) {
            pes[r] += __shfl_xor(pes[r], m);
            ped[r] += __shfl_xor(ped[r], m);
        }
    }
    if (li == 0) {
#pragma unroll
        for (int r = 0; r < 4; ++r) {
            const int row = ibase + grp * 4 + r;
            Rt[w * NN + row] = __builtin_amdgcn_exp2f(-0.8f * LOG2E * pes[r]);
            Bt[w * NN + row] = __builtin_amdgcn_exp2f(LOG2E * ped[r]);
            Dt[w * NN + row] = __builtin_amdgcn_exp2f(0.2f * LOG2E * ped[r]);
        }
    }
    unsigned short* tw = &ttile[w][0][0];
    {
        uint2 v0; v0.x = pk2(c0[0], c0[1]); v0.y = pk2(c0[2], c0[3]);
        uint2 v1; v1.x = pk2(c1[0], c1[1]); v1.y = pk2(c1[2], c1[3]);
        *(uint2*)&tw[li * 16 + grp * 4] = v0;
        *(uint2*)&tw[(li + 16) * 16 + grp * 4] = v1;
    }
    __syncthreads();
    const int d = lane >> 1, half = lane & 1;
    u32x4 v = *(const u32x4*)&ttile[w][d][half * 8];
    *(u32x4*)(hT + (size_t)(w * 32 + d) * NN + ibase + half * 8) = v;
}

// per-step register payload (loaded 1 step ahead, 2 slots, no copies)
struct SR {
    short8 t00, t01, t10, t11;       // hT rows d=li (ks=0,1), d=li+16 (ks=0,1)
    f32x4 B0a, B0b, B1a, B1b;        // B slices: ks=0 (8 j), ks=1
    f32x4 D0a, D0b, D1a, D1b;        // D slices
};

// q = adj * max(B, R*D): mul,max,sub,and per element + cvt_pk per pair.
__device__ __forceinline__ short8 buildQ(float R,
                                         const f32x4 Ba, const f32x4 Bb,
                                         const f32x4 Da, const f32x4 Db,
                                         const i32x4 q0, const i32x4 q1) {
    float p[8];
#pragma unroll
    for (int e = 0; e < 4; ++e) {
        const float m = fmaxf(Ba[e], R * Da[e]);
        p[e] = __builtin_bit_cast(float, __builtin_bit_cast(unsigned, m) & (0u - (unsigned)q0[e]));
    }
#pragma unroll
    for (int e = 0; e < 4; ++e) {
        const float m = fmaxf(Bb[e], R * Db[e]);
        p[4 + e] = __builtin_bit_cast(float, __builtin_bit_cast(unsigned, m) & (0u - (unsigned)q1[e]));
    }
    u32x4 u = {pk2(p[0], p[1]), pk2(p[2], p[3]), pk2(p[4], p[5]), pk2(p[6], p[7])};
    return __builtin_bit_cast(short8, u);
}

// Kernel 3: grid (64 i-tiles, SJ) x 256 thr, wave = head, 64 rows/block.
// Fully-unrolled counted-vmcnt pipeline: adj triple-buffered global_load_lds
// (2 steps ahead), tables in 2 SR register slots (1 step ahead). Per step:
// issue loadR(t+1)[12] + stage(t+2)[4]; compute (zero vmem); vmcnt(4) leaves
// stage(t+2) in flight; raw s_barrier. XOR chunk swizzle c = p ^ (row&15) on
// global source (LDS linear, rule 21), inverted on ds_read (2-way = free).
__global__ __launch_bounds__(256, 2) void k3_main(
        const int* __restrict__ adj, const unsigned short* __restrict__ hT,
        const float* __restrict__ Rt, const float* __restrict__ Bt,
        const float* __restrict__ Dt,
        float* __restrict__ numer, float* __restrict__ denom) {
    __shared__ unsigned int adjbuf[3][ROWS * 64];   // 3 x 16 KB

    const int ibase = blockIdx.x * ROWS;
    const int jstart = blockIdx.y * JCH;
    const int head = threadIdx.x >> 6;
    const int lane = threadIdx.x & 63;
    const int grp = lane >> 4, li = lane & 15;

    float Rv[4];
#pragma unroll
    for (int g = 0; g < 4; ++g) Rv[g] = Rt[head * NN + ibase + g * 16 + li];
    const unsigned short* h0 = hT + (size_t)(head * 32 + li) * NN;
    const unsigned short* h1 = hT + (size_t)(head * 32 + 16 + li) * NN;
    const float* Bp = Bt + head * NN;
    const float* Dp = Dt + head * NN;
    const unsigned int* adju = (const unsigned int*)adj;

    f32x4 c[4][2], dn[4];
#pragma unroll
    for (int g = 0; g < 4; ++g) {
        c[g][0] = f32x4{0.f,0.f,0.f,0.f};
        c[g][1] = f32x4{0.f,0.f,0.f,0.f};
        dn[g] = f32x4{0.f,0.f,0.f,0.f};
    }
    short8 bones;
#pragma unroll
    for (int e = 0; e < 8; ++e) bones[e] = (short)0x3F80;  // bf16 1.0

    // wave `head` stages rows head*16..+16 (4 rows per issue, 4 issues)
    auto stage = [&](int slot, int jb) {
#pragma unroll
        for (int k = 0; k < 4; ++k) {
            const int Rw = head * 16 + k * 4 + grp;
            const int cc = li ^ (Rw & 15);
            const unsigned int* g = adju + (size_t)(ibase + Rw) * NN + jb + cc * 4;
            __builtin_amdgcn_global_load_lds(g, &adjbuf[slot][(head * 16 + k * 4) * 64], 16, 0, 0);
        }
    };
    auto loadR = [&](int jb) {
        SR r;
        r.t00 = *(const short8*)(h0 + jb + grp * 8);
        r.t01 = *(const short8*)(h0 + jb + 32 + grp * 8);
        r.t10 = *(const short8*)(h1 + jb + grp * 8);
        r.t11 = *(const short8*)(h1 + jb + 32 + grp * 8);
        r.B0a = *(const f32x4*)(Bp + jb + grp * 8);
        r.B0b = *(const f32x4*)(Bp + jb + grp * 8 + 4);
        r.B1a = *(const f32x4*)(Bp + jb + 32 + grp * 8);
        r.B1b = *(const f32x4*)(Bp + jb + 32 + grp * 8 + 4);
        r.D0a = *(const f32x4*)(Dp + jb + grp * 8);
        r.D0b = *(const f32x4*)(Dp + jb + grp * 8 + 4);
        r.D1a = *(const f32x4*)(Dp + jb + 32 + grp * 8);
        r.D1b = *(const f32x4*)(Dp + jb + 32 + grp * 8 + 4);
        return r;
    };
    auto compute = [&](const unsigned int* buf, const SR& S) {
#pragma unroll
        for (int ks = 0; ks < 2; ++ks) {
            const short8 tA = ks ? S.t01 : S.t00;
            const short8 tB = ks ? S.t11 : S.t10;
            const f32x4 Ba = ks ? S.B1a : S.B0a;
            const f32x4 Bb = ks ? S.B1b : S.B0b;
            const f32x4 Da = ks ? S.D1a : S.D0a;
            const f32x4 Db = ks ? S.D1b : S.D0b;
            const int cb = ks * 8 + grp * 2;
#pragma unroll
            for (int g = 0; g < 4; ++g) {
                const int row = li + g * 16;
                const i32x4 q0 = *(const i32x4*)&buf[row * 64 + (cb ^ li) * 4];
                const i32x4 q1 = *(const i32x4*)&buf[row * 64 + ((cb + 1) ^ li) * 4];
                const short8 A = buildQ(Rv[g], Ba, Bb, Da, Db, q0, q1);
                c[g][0] = __builtin_amdgcn_mfma_f32_16x16x32_bf16(A, tA, c[g][0], 0, 0, 0);
                c[g][1] = __builtin_amdgcn_mfma_f32_16x16x32_bf16(A, tB, c[g][1], 0, 0, 0);
                dn[g] = __builtin_amdgcn_mfma_f32_16x16x32_bf16(A, bones, dn[g], 0, 0, 0);
            }
        }
    };

    SR S[2];
    stage(0, jstart);                 // 4 issues (oldest)
    S[0] = loadR(jstart);             // 12 issues
    stage(1, jstart + JSTEP);         // 4 issues (newest)
    asm volatile("s_waitcnt vmcnt(4)" ::: "memory");   // slot0 + S0 ready
    __builtin_amdgcn_s_barrier();
    __builtin_amdgcn_sched_barrier(0);

#pragma unroll
    for (int t = 0; t < NSTEPS; ++t) {
        if (t + 1 < NSTEPS) S[(t + 1) & 1] = loadR(jstart + (t + 1) * JSTEP);
        if (t + 2 < NSTEPS) stage((t + 2) % 3, jstart + (t + 2) * JSTEP);

        compute(&adjbuf[t % 3][0], S[t & 1]);

        if (t + 2 < NSTEPS) {
            asm volatile("s_waitcnt vmcnt(4)" ::: "memory");  // drains stage(t+1)+S(t+1)
        } else if (t + 1 < NSTEPS) {
            asm volatile("s_waitcnt vmcnt(0)" ::: "memory");  // last prefetches
        }
        if (t + 1 < NSTEPS) {
            __builtin_amdgcn_s_barrier();
            __builtin_amdgcn_sched_barrier(0);
        }
    }

    // Epilogue: C layout col=li, row=grp*4+r within each 16-row group.
    float* nb = numer + head * 32 + li;
#pragma unroll
    for (int g = 0; g < 4; ++g) {
        const int r0 = ibase + g * 16 + grp * 4;
#pragma unroll
        for (int r = 0; r < 4; ++r) {
            atomicAdd(nb + (size_t)(r0 + r) * 128, c[g][0][r]);
            atomicAdd(nb + (size_t)(r0 + r) * 128 + 16, c[g][1][r]);
        }
    }
    if (li == 0) {
#pragma unroll
        for (int g = 0; g < 4; ++g) {
            const int r0 = ibase + g * 16 + grp * 4;
#pragma unroll
            for (int r = 0; r < 4; ++r)
                atomicAdd(denom + (r0 + r) * 4 + head, dn[g][r]);
        }
    }
}

// Kernel 4: out = numer / denom
__global__ __launch_bounds__(256) void k4_fin(const float* __restrict__ numer,
                                              const float* __restrict__ denom,
                                              float* __restrict__ out) {
    const int idx = blockIdx.x * 256 + threadIdx.x;
    const int node = idx >> 7;
    const int headc = (idx & 127) >> 5;
    out[idx] = numer[idx] / denom[node * 4 + headc];
}

extern "C" void kernel_launch(void* const* d_in, const int* in_sizes, int n_in,
                              void* d_out, int out_size, void* d_ws, size_t ws_size,
                              hipStream_t stream) {
    const float* x = (const float*)d_in[0];
    const int* adj = (const int*)d_in[1];
    const float* W = (const float*)d_in[2];
    const float* asrc = (const float*)d_in[3];
    const float* adst = (const float*)d_in[4];
    float* out = (float*)d_out;

    char* ws = (char*)d_ws;
    float* numer = (float*)ws;                                     // 2 MB
    float* denom = (float*)(ws + (size_t)2097152);                 // 64 KB
    float* Rt = (float*)(ws + (size_t)2097152 + 65536);            // 64 KB
    float* Bt = (float*)(ws + (size_t)2097152 + 131072);           // 64 KB
    float* Dt = (float*)(ws + (size_t)2097152 + 196608);           // 64 KB
    unsigned short* hT = (unsigned short*)(ws + (size_t)2097152 + 262144);  // 1 MB

    (void)hipMemsetAsync(numer, 0, 2097152 + 65536, stream);       // zero accumulators
    k1_proj<<<256, 256, 0, stream>>>(x, W, asrc, adst, hT, Rt, Bt, Dt);
    k3_main<<<dim3(NN / ROWS, SJ), 256, 0, stream>>>(adj, hT, Rt, Bt, Dt, numer, denom);
    k4_fin<<<2048, 256, 0, stream>>>(numer, denom, out);
}